// Round 10
// baseline (188.487 us; speedup 1.0000x reference)
//
#include <hip/hip_runtime.h>
#include <cstdint>
#include <cstddef>

// Problem constants (B=32, D=256, H=32, W=32, K=1024), N = B*H*W = 32768.
// MFMA path: fp32 -> 3x bf16 split; 6 concat-K segments -> bf16 GEMM
// M=32768 N=1024 K=1536; error ~ fp32 accumulation (numpy-grade).
//
// History: r5 128² 716TF; r6 deep pipeline REGRESSED; r7 dbuf neutral (m97
// ceiling); r8 256²/4-phase counted-vmcnt 124µs (bank-conflict 9.4M);
// r9 fixed swizzle (row bits 1-2) -> 0 conflicts, 114.9µs, MfmaUtil 38%.
// Cycle audit: 16x16x32 MFMA = ~19.4 cyc/SIMD; phase = 620 cyc pipe work vs
// ~1430 cyc measured -> ~800 cyc/phase sync overhead (2 barriers + read lat).
// r10: merge mh halves -> 2 fat phases/tile (32 MFMA each), barriers 8->4
// per tile; launch_bounds(512,1) lifts the 128-VGPR cap (r9 sat at 124).

typedef __attribute__((ext_vector_type(8))) short bf16x8;
typedef __attribute__((ext_vector_type(4))) float f32x4;

#define GL2LDS(g, l) __builtin_amdgcn_global_load_lds( \
    (__attribute__((address_space(1))) const void*)(g), \
    (__attribute__((address_space(3))) void*)(l), 16, 0, 0)

__device__ __forceinline__ unsigned short rne_bf16(float f) {
    unsigned u = __float_as_uint(f);
    return (unsigned short)((u + 0x7FFFu + ((u >> 16) & 1u)) >> 16);
}
__device__ __forceinline__ float bf16_to_f(unsigned short h) {
    return __uint_as_float((unsigned)h << 16);
}

// ---------------------------------------------------------------------------
// codebook row norms ||c_k||^2
// ---------------------------------------------------------------------------
__global__ __launch_bounds__(256)
void vq_cnorm_kernel(const float* __restrict__ cb, float* __restrict__ cnorm)
{
    const int k = blockIdx.x * 256 + threadIdx.x;  // grid=4
    const float4* row = reinterpret_cast<const float4*>(cb + (size_t)k * 256);
    float s0 = 0.f, s1 = 0.f, s2 = 0.f, s3 = 0.f;
#pragma unroll 8
    for (int i = 0; i < 64; ++i) {
        float4 v = row[i];
        s0 = fmaf(v.x, v.x, s0);
        s1 = fmaf(v.y, v.y, s1);
        s2 = fmaf(v.z, v.z, s2);
        s3 = fmaf(v.w, v.w, s3);
    }
    cnorm[k] = (s0 + s1) + (s2 + s3);
}

// ---------------------------------------------------------------------------
// codebook split: [1024][256] fp32 -> c0,c1,c2 bf16
// ---------------------------------------------------------------------------
__global__ __launch_bounds__(256)
void vq_csplit_kernel(const float* __restrict__ cb, unsigned short* __restrict__ c0,
                      unsigned short* __restrict__ c1, unsigned short* __restrict__ c2)
{
    const int idx = blockIdx.x * 256 + threadIdx.x;   // grid 256
    float4 v = reinterpret_cast<const float4*>(cb)[idx];
    float f[4] = { v.x, v.y, v.z, v.w };
    ushort4 h0, h1, h2;
    unsigned short* p0[4] = { &h0.x, &h0.y, &h0.z, &h0.w };
    unsigned short* p1[4] = { &h1.x, &h1.y, &h1.z, &h1.w };
    unsigned short* p2[4] = { &h2.x, &h2.y, &h2.z, &h2.w };
#pragma unroll
    for (int j = 0; j < 4; ++j) {
        unsigned short b0 = rne_bf16(f[j]); float r1 = f[j] - bf16_to_f(b0);
        unsigned short b1 = rne_bf16(r1);   float r2 = r1 - bf16_to_f(b1);
        unsigned short b2 = rne_bf16(r2);
        *p0[j] = b0; *p1[j] = b1; *p2[j] = b2;
    }
    reinterpret_cast<ushort4*>(c0)[idx] = h0;
    reinterpret_cast<ushort4*>(c1)[idx] = h1;
    reinterpret_cast<ushort4*>(c2)[idx] = h2;
}

// ---------------------------------------------------------------------------
// z split+transpose: z[b][d][hw] fp32 -> z0,z1,z2 bf16 [n][d]
// ---------------------------------------------------------------------------
__global__ __launch_bounds__(256)
void vq_zsplit_kernel(const float* __restrict__ z, unsigned short* __restrict__ z0,
                      unsigned short* __restrict__ z1, unsigned short* __restrict__ z2)
{
    __shared__ float zl[64 * 264];
    const int t = threadIdx.x, blk = blockIdx.x;        // 512 blocks
    const int b = blk >> 4, hw0 = (blk & 15) << 6;
    const float* zb = z + ((size_t)b << 18) + hw0;
#pragma unroll 8
    for (int i = 0; i < 64; ++i) {
        int idx = i * 256 + t;
        int d = idx >> 6, hwl = idx & 63;
        zl[hwl * 264 + d] = zb[(size_t)d * 1024 + hwl];
    }
    __syncthreads();
    const int n0 = (b << 10) + hw0;
#pragma unroll
    for (int p = 0; p < 8; ++p) {
        const int hwl = p * 8 + (t >> 5);
        const int d0 = (t & 31) * 8;
        const float* src = &zl[hwl * 264 + d0];
        unsigned short h0[8], h1[8], h2[8];
#pragma unroll
        for (int j = 0; j < 8; ++j) {
            float f = src[j];
            unsigned short b0 = rne_bf16(f);  float r1 = f - bf16_to_f(b0);
            unsigned short b1 = rne_bf16(r1); float r2 = r1 - bf16_to_f(b1);
            unsigned short b2 = rne_bf16(r2);
            h0[j] = b0; h1[j] = b1; h2[j] = b2;
        }
        const size_t o = (size_t)(n0 + hwl) * 256 + d0;
        ushort4 a;
        a = ushort4{h0[0],h0[1],h0[2],h0[3]}; *reinterpret_cast<ushort4*>(z0 + o)     = a;
        a = ushort4{h0[4],h0[5],h0[6],h0[7]}; *reinterpret_cast<ushort4*>(z0 + o + 4) = a;
        a = ushort4{h1[0],h1[1],h1[2],h1[3]}; *reinterpret_cast<ushort4*>(z1 + o)     = a;
        a = ushort4{h1[4],h1[5],h1[6],h1[7]}; *reinterpret_cast<ushort4*>(z1 + o + 4) = a;
        a = ushort4{h2[0],h2[1],h2[2],h2[3]}; *reinterpret_cast<ushort4*>(z2 + o)     = a;
        a = ushort4{h2[4],h2[5],h2[6],h2[7]}; *reinterpret_cast<ushort4*>(z2 + o + 4) = a;
    }
}

// ---------------------------------------------------------------------------
// MFMA GEMM + fused argmin — 256² tile, 8 waves, 2 FAT phases/K-tile.
//
// LDS: Ld[buf2][mat2][kk2][256x32] bf16 = 128KB (1 block/CU, 8 waves).
// Phase (t, kk): ds_read 8 A-frags + 4 B-frags -> stage A,B planes of
// (t+1, kk) into buf^1 -> barrier -> setprio(1) 32 MFMA setprio(0) ->
// vmcnt(4) -> barrier. Counted vmcnt never 0 until the tail (T4).
// vmcnt ledger (4 gl2lds/thread per phase): prologue stages t0 (8), waits
// vmcnt(4) [t0 kk0 in]; each phase issues 4, waits vmcnt(4) [oldest plane
// in, staged ~1.5 fat phases earlier > HBM latency].
// Hazards: stage t+1 -> buf^1 while reading buf; buf^1 last read in tile
// t-1, barrier-separated (same as r9).
//
// Swizzle (r9-proven, 0 conflicts): bank = (row&1)*16 + slot*4; store chunk
// c of row r at slot c ^ ((r>>1)&3); gl2lds writes linearly -> GLOBAL source
// chunk pre-swizzled (selem), ds_read applies same XOR (fco).
// Accumulation: per acc element kk0 then kk1 per tile, tiles ascending ==
// r9 exactly -> bit-identical distances.
// launch_bounds(512,1): lifts 128-VGPR cap (need ~190); LDS still pins
// 1 block/CU = 2 waves/SIMD, each <=256 VGPR -> occupancy unchanged.
// ---------------------------------------------------------------------------
__global__ __launch_bounds__(512, 1)
void vq_mfma_argmin_kernel(const unsigned short* __restrict__ zp,
                           const unsigned short* __restrict__ cp,
                           const float* __restrict__ cnorm,
                           unsigned long long* __restrict__ packed)
{
    __shared__ unsigned short Ld[2][2][2][256 * 32];   // 128KB

    const int tid = threadIdx.x, l = tid & 63, w = tid >> 6;
    const int wr = w >> 2, wc = w & 3;                 // 2 x 4 wave grid
    const int nid = ((blockIdx.x & 7) << 6) | (blockIdx.x >> 3);  // XCD swizzle (512%8==0)
    const int bm = nid >> 2, bn = nid & 3;             // 128 x 4 tiles
    const int arow = bm * 256, brow = bn * 256;

    f32x4 acc[8][4];
#pragma unroll
    for (int m = 0; m < 8; ++m)
#pragma unroll
        for (int n = 0; n < 4; ++n) acc[m][n] = f32x4{0.f, 0.f, 0.f, 0.f};

    // staging lane geometry: lane l -> row l>>2, slot l&3; source chunk
    // pre-swizzled by row bits 1-2 ((l>>3)&3) so stored slot = c ^ ((r>>1)&3)
    const int srow  = l >> 2;
    const int selem = (((l & 3) ^ ((l >> 3) & 3))) << 3;

    // fragment-read: chunk hi4 of row r at slot hi4 ^ ((r>>1)&3); r ≡ lo16 (16)
    const int lo16 = l & 15, hi4 = l >> 4;
    const int fco = ((hi4 ^ ((lo16 >> 1) & 3))) << 3;

    // segment tables packed as nibbles: A {0,1,2,0,1,0}, B {0,0,0,1,1,2}
#define STAGE(tt, mat, kk) do {                                               \
    const int seg_ = (tt) >> 2;                                               \
    const unsigned short* S_ = (mat)                                          \
        ? cp + (size_t)((0x211000 >> (seg_ << 2)) & 3) * 262144u              \
        : zp + (size_t)((0x010210 >> (seg_ << 2)) & 3) * 8388608u;            \
    const int R_  = (mat) ? brow : arow;                                      \
    const int KO_ = (((tt) & 3) << 6) + ((kk) << 5) + selem;                  \
    GL2LDS(S_ + (size_t)(R_ + (w * 2 + 0) * 16 + srow) * 256 + KO_,           \
           &Ld[(tt) & 1][mat][kk][(w * 2 + 0) * 512]);                        \
    GL2LDS(S_ + (size_t)(R_ + (w * 2 + 1) * 16 + srow) * 256 + KO_,           \
           &Ld[(tt) & 1][mat][kk][(w * 2 + 1) * 512]);                        \
} while (0)

#define VM4  asm volatile("s_waitcnt vmcnt(4)"  ::: "memory")
#define VM0  asm volatile("s_waitcnt vmcnt(0)"  ::: "memory")
#define NOPS ((void)0)
#define SBAR do { asm volatile("" ::: "memory");                              \
                  __builtin_amdgcn_s_barrier();                               \
                  __builtin_amdgcn_sched_barrier(0); } while (0)

    // fat phase: 12 ds_read + optional stage + barrier + 32 MFMA + wait + barrier
#define PH2(t, kk, STAGESTMT, VMSTMT) do {                                    \
    const unsigned short* Ap_ = &Ld[(t) & 1][0][kk][0];                       \
    const unsigned short* Bp_ = &Ld[(t) & 1][1][kk][0];                       \
    bf16x8 a0 = *(const bf16x8*)&Ap_[(wr*128 + 0*16 + lo16)*32 + fco];        \
    bf16x8 a1 = *(const bf16x8*)&Ap_[(wr*128 + 1*16 + lo16)*32 + fco];        \
    bf16x8 a2 = *(const bf16x8*)&Ap_[(wr*128 + 2*16 + lo16)*32 + fco];        \
    bf16x8 a3 = *(const bf16x8*)&Ap_[(wr*128 + 3*16 + lo16)*32 + fco];        \
    bf16x8 a4 = *(const bf16x8*)&Ap_[(wr*128 + 4*16 + lo16)*32 + fco];        \
    bf16x8 a5 = *(const bf16x8*)&Ap_[(wr*128 + 5*16 + lo16)*32 + fco];        \
    bf16x8 a6 = *(const bf16x8*)&Ap_[(wr*128 + 6*16 + lo16)*32 + fco];        \
    bf16x8 a7 = *(const bf16x8*)&Ap_[(wr*128 + 7*16 + lo16)*32 + fco];        \
    bf16x8 b0 = *(const bf16x8*)&Bp_[(wc*64 + 0*16 + lo16)*32 + fco];         \
    bf16x8 b1 = *(const bf16x8*)&Bp_[(wc*64 + 1*16 + lo16)*32 + fco];         \
    bf16x8 b2 = *(const bf16x8*)&Bp_[(wc*64 + 2*16 + lo16)*32 + fco];         \
    bf16x8 b3 = *(const bf16x8*)&Bp_[(wc*64 + 3*16 + lo16)*32 + fco];         \
    STAGESTMT;                                                                \
    SBAR;                                                                     \
    __builtin_amdgcn_s_setprio(1);                                            \
    acc[0][0] = __builtin_amdgcn_mfma_f32_16x16x32_bf16(a0, b0, acc[0][0], 0,0,0); \
    acc[0][1] = __builtin_amdgcn_mfma_f32_16x16x32_bf16(a0, b1, acc[0][1], 0,0,0); \
    acc[0][2] = __builtin_amdgcn_mfma_f32_16x16x32_bf16(a0, b2, acc[0][2], 0,0,0); \
    acc[0][3] = __builtin_amdgcn_mfma_f32_16x16x32_bf16(a0, b3, acc[0][3], 0,0,0); \
    acc[1][0] = __builtin_amdgcn_mfma_f32_16x16x32_bf16(a1, b0, acc[1][0], 0,0,0); \
    acc[1][1] = __builtin_amdgcn_mfma_f32_16x16x32_bf16(a1, b1, acc[1][1], 0,0,0); \
    acc[1][2] = __builtin_amdgcn_mfma_f32_16x16x32_bf16(a1, b2, acc[1][2], 0,0,0); \
    acc[1][3] = __builtin_amdgcn_mfma_f32_16x16x32_bf16(a1, b3, acc[1][3], 0,0,0); \
    acc[2][0] = __builtin_amdgcn_mfma_f32_16x16x32_bf16(a2, b0, acc[2][0], 0,0,0); \
    acc[2][1] = __builtin_amdgcn_mfma_f32_16x16x32_bf16(a2, b1, acc[2][1], 0,0,0); \
    acc[2][2] = __builtin_amdgcn_mfma_f32_16x16x32_bf16(a2, b2, acc[2][2], 0,0,0); \
    acc[2][3] = __builtin_amdgcn_mfma_f32_16x16x32_bf16(a2, b3, acc[2][3], 0,0,0); \
    acc[3][0] = __builtin_amdgcn_mfma_f32_16x16x32_bf16(a3, b0, acc[3][0], 0,0,0); \
    acc[3][1] = __builtin_amdgcn_mfma_f32_16x16x32_bf16(a3, b1, acc[3][1], 0,0,0); \
    acc[3][2] = __builtin_amdgcn_mfma_f32_16x16x32_bf16(a3, b2, acc[3][2], 0,0,0); \
    acc[3][3] = __builtin_amdgcn_mfma_f32_16x16x32_bf16(a3, b3, acc[3][3], 0,0,0); \
    acc[4][0] = __builtin_amdgcn_mfma_f32_16x16x32_bf16(a4, b0, acc[4][0], 0,0,0); \
    acc[4][1] = __builtin_amdgcn_mfma_f32_16x16x32_bf16(a4, b1, acc[4][1], 0,0,0); \
    acc[4][2] = __builtin_amdgcn_mfma_f32_16x16x32_bf16(a4, b2, acc[4][2], 0,0,0); \
    acc[4][3] = __builtin_amdgcn_mfma_f32_16x16x32_bf16(a4, b3, acc[4][3], 0,0,0); \
    acc[5][0] = __builtin_amdgcn_mfma_f32_16x16x32_bf16(a5, b0, acc[5][0], 0,0,0); \
    acc[5][1] = __builtin_amdgcn_mfma_f32_16x16x32_bf16(a5, b1, acc[5][1], 0,0,0); \
    acc[5][2] = __builtin_amdgcn_mfma_f32_16x16x32_bf16(a5, b2, acc[5][2], 0,0,0); \
    acc[5][3] = __builtin_amdgcn_mfma_f32_16x16x32_bf16(a5, b3, acc[5][3], 0,0,0); \
    acc[6][0] = __builtin_amdgcn_mfma_f32_16x16x32_bf16(a6, b0, acc[6][0], 0,0,0); \
    acc[6][1] = __builtin_amdgcn_mfma_f32_16x16x32_bf16(a6, b1, acc[6][1], 0,0,0); \
    acc[6][2] = __builtin_amdgcn_mfma_f32_16x16x32_bf16(a6, b2, acc[6][2], 0,0,0); \
    acc[6][3] = __builtin_amdgcn_mfma_f32_16x16x32_bf16(a6, b3, acc[6][3], 0,0,0); \
    acc[7][0] = __builtin_amdgcn_mfma_f32_16x16x32_bf16(a7, b0, acc[7][0], 0,0,0); \
    acc[7][1] = __builtin_amdgcn_mfma_f32_16x16x32_bf16(a7, b1, acc[7][1], 0,0,0); \
    acc[7][2] = __builtin_amdgcn_mfma_f32_16x16x32_bf16(a7, b2, acc[7][2], 0,0,0); \
    acc[7][3] = __builtin_amdgcn_mfma_f32_16x16x32_bf16(a7, b3, acc[7][3], 0,0,0); \
    __builtin_amdgcn_s_setprio(0);                                            \
    VMSTMT;                                                                   \
    SBAR;                                                                     \
} while (0)

#define TILE2(t, S0, S1, V1, V2)                                              \
    PH2(t, 0, S0, V1);                                                        \
    PH2(t, 1, S1, V2)

    // prologue: stage tile 0 fully (8 loads); wait its kk0 (leave 4); barrier
    STAGE(0, 0, 0); STAGE(0, 1, 0); STAGE(0, 0, 1); STAGE(0, 1, 1);
    VM4;
    SBAR;

#pragma unroll 2
    for (int t = 0; t <= 22; ++t) {
        TILE2(t, { STAGE(t + 1, 0, 0); STAGE(t + 1, 1, 0); },
                 { STAGE(t + 1, 0, 1); STAGE(t + 1, 1, 1); }, VM4, VM4);
    }
    TILE2(23, NOPS, NOPS, VM0, NOPS);

#undef TILE2
#undef PH2
#undef STAGE

    // epilogue: fused argmin. col = brow + wc*64 + n*16 + lo16
    int coln[4]; float cnv[4];
#pragma unroll
    for (int n = 0; n < 4; ++n) {
        coln[n] = brow + wc * 64 + n * 16 + lo16;
        cnv[n] = cnorm[coln[n]];
    }
#pragma unroll
    for (int m = 0; m < 8; ++m) {
#pragma unroll
        for (int j = 0; j < 4; ++j) {
            unsigned long long best = 0xFFFFFFFFFFFFFFFFull;
#pragma unroll
            for (int n = 0; n < 4; ++n) {
                float d = fmaf(-2.0f, acc[m][n][j], cnv[n]);
                unsigned u = __float_as_uint(d);
                u = (u & 0x80000000u) ? ~u : (u | 0x80000000u);   // order-preserving map
                unsigned long long pk = ((unsigned long long)u << 32) | (unsigned)coln[n];
                best = pk < best ? pk : best;
            }
#pragma unroll
            for (int mask = 1; mask <= 8; mask <<= 1) {
                unsigned long long o = __shfl_xor(best, mask, 64);
                best = o < best ? o : best;
            }
            if (lo16 == 0) {
                const int row = arow + wr * 128 + m * 16 + hi4 * 4 + j;
                atomicMin(&packed[row], best);
            }
        }
    }
}

// ---------------------------------------------------------------------------
// gather (packed): z_q write, out_idx write, vq_loss accumulate
// ---------------------------------------------------------------------------
__global__ __launch_bounds__(256, 2)
void vq_gather_packed_kernel(const float* __restrict__ cb, const float* __restrict__ z,
                             const unsigned long long* __restrict__ packed,
                             float* __restrict__ out_zq, float* __restrict__ out_idx,
                             float* __restrict__ loss)
{
    __shared__ float rows[64 * 257];
    __shared__ int   ks[64];
    __shared__ float wsum[4];

    const int t   = threadIdx.x;
    const int blk = blockIdx.x;            // 512 blocks
    const int b   = blk >> 4;
    const int hw0 = (blk & 15) << 6;
    const int n0  = blk << 6;

    if (t < 64) {
        const int k = (int)(packed[n0 + t] & 0xFFFFFFFFull);
        ks[t] = k;
        out_idx[n0 + t] = (float)k;
    }
    __syncthreads();

#pragma unroll 4
    for (int i = 0; i < 64; ++i) {
        rows[i * 257 + t] = cb[(size_t)ks[i] * 256 + t];
    }
    __syncthreads();

    const int dq = t >> 6;
    const int hw = t & 63;
    const size_t obase = ((size_t)b << 18) + hw0 + hw;
    float sum = 0.f;
#pragma unroll 4
    for (int dd = 0; dd < 64; ++dd) {
        const int d = (dq << 6) + dd;
        const float  q  = rows[hw * 257 + d];
        const size_t a  = obase + (size_t)d * 1024;
        const float  zv = z[a];
        out_zq[a] = q;
        const float diff = q - zv;
        sum = fmaf(diff, diff, sum);
    }
#pragma unroll
    for (int m = 1; m <= 32; m <<= 1) sum += __shfl_xor(sum, m, 64);
    if ((t & 63) == 0) wsum[t >> 6] = sum;
    __syncthreads();
    if (t == 0) {
        const float s = (wsum[0] + wsum[1]) + (wsum[2] + wsum[3]);
        atomicAdd(loss, s * (1.25f / 8388608.0f));   // (1+0.25)*SSE/(B*D*H*W)
    }
}

// ===========================================================================
// FALLBACK PATH (ws too small): round-3 fp32 VALU kernels, known-passing.
// ===========================================================================
__global__ __launch_bounds__(256)
void vq_transpose_kernel(const float* __restrict__ cb, float* __restrict__ ctT)
{
    __shared__ float tile[64 * 65];
    const int t  = threadIdx.x;
    const int kb = blockIdx.x >> 2, db = blockIdx.x & 3;
    const int k0 = kb << 6, d0 = db << 6;
#pragma unroll
    for (int i = 0; i < 16; ++i) {
        int idx = i * 256 + t;
        int r = idx >> 6, c = idx & 63;
        tile[r * 65 + c] = cb[(size_t)(k0 + r) * 256 + d0 + c];
    }
    __syncthreads();
#pragma unroll
    for (int i = 0; i < 16; ++i) {
        int idx = i * 256 + t;
        int r = idx >> 6, c = idx & 63;
        ctT[(size_t)(d0 + r) * 1024 + k0 + c] = tile[c * 65 + r];
    }
}

__global__ __launch_bounds__(512, 2)
void vq_argmin_kernel(const float* __restrict__ z, const float* __restrict__ ctT,
                      const float* __restrict__ cnorm, int* __restrict__ codes,
                      float* __restrict__ out_idx)
{
    __shared__ float zt[256 * 64];
    __shared__ float ct[16 * 256];
    const int t = threadIdx.x, tx = t & 63, ty = t >> 6, p0 = ty << 3;
    const int blk = blockIdx.x, b = blk >> 4, hw0 = (blk & 15) << 6;
    const float* zbase = z + ((size_t)b << 18) + hw0;
#pragma unroll
    for (int i = 0; i < 8; ++i) {
        int idx = i * 512 + t;
        int d = idx >> 4, c4 = (idx & 15) << 2;
        float4 v = *reinterpret_cast<const float4*>(zbase + (size_t)d * 1024 + c4);
        *reinterpret_cast<float4*>(&zt[d * 64 + c4]) = v;
    }
    float minv[8]; int mini[8];
#pragma unroll
    for (int i = 0; i < 8; ++i) { minv[i] = 3.0e38f; mini[i] = 0; }
    const float* zrd = &zt[p0];
    const float* crd = &ct[tx << 2];
    for (int kt = 0; kt < 4; ++kt) {
        const int k0 = kt << 8;
        float acc[8][4];
#pragma unroll
        for (int i = 0; i < 8; ++i)
#pragma unroll
            for (int j = 0; j < 4; ++j) acc[i][j] = 0.f;
        for (int dc = 0; dc < 16; ++dc) {
            const int d0 = dc << 4;
            __syncthreads();
#pragma unroll
            for (int i = 0; i < 2; ++i) {
                int idx = i * 512 + t;
                int r = idx >> 6, c4 = (idx & 63) << 2;
                float4 v = *reinterpret_cast<const float4*>(ctT + (size_t)(d0 + r) * 1024 + k0 + c4);
                *reinterpret_cast<float4*>(&ct[r * 256 + c4]) = v;
            }
            __syncthreads();
            const float* zp = zrd + d0 * 64;
#pragma unroll
            for (int d = 0; d < 16; ++d) {
                float4 za = *reinterpret_cast<const float4*>(zp + d * 64);
                float4 zb = *reinterpret_cast<const float4*>(zp + d * 64 + 4);
                float4 cc = *reinterpret_cast<const float4*>(crd + d * 256);
#define VQ_FMA_ROW(ii, zv)                          \
                acc[ii][0] = fmaf(zv, cc.x, acc[ii][0]); \
                acc[ii][1] = fmaf(zv, cc.y, acc[ii][1]); \
                acc[ii][2] = fmaf(zv, cc.z, acc[ii][2]); \
                acc[ii][3] = fmaf(zv, cc.w, acc[ii][3]);
                VQ_FMA_ROW(0, za.x) VQ_FMA_ROW(1, za.y) VQ_FMA_ROW(2, za.z) VQ_FMA_ROW(3, za.w)
                VQ_FMA_ROW(4, zb.x) VQ_FMA_ROW(5, zb.y) VQ_FMA_ROW(6, zb.z) VQ_FMA_ROW(7, zb.w)
#undef VQ_FMA_ROW
            }
        }
#pragma unroll
        for (int j = 0; j < 4; ++j) {
            const int k = k0 + (tx << 2) + j;
            const float cn = cnorm[k];
#pragma unroll
            for (int i = 0; i < 8; ++i) {
                float dist = fmaf(-2.0f, acc[i][j], cn);
                if (dist < minv[i]) { minv[i] = dist; mini[i] = k; }
            }
        }
    }
#pragma unroll
    for (int m = 1; m <= 32; m <<= 1) {
#pragma unroll
        for (int i = 0; i < 8; ++i) {
            float ov = __shfl_xor(minv[i], m, 64);
            int   oi = __shfl_xor(mini[i], m, 64);
            if (ov < minv[i] || (ov == minv[i] && oi < mini[i])) { minv[i] = ov; mini[i] = oi; }
        }
    }
    if (tx == 0) {
        const int n0 = (blk << 6) + p0;
#pragma unroll
        for (int i = 0; i < 8; ++i) {
            codes[n0 + i]   = mini[i];
            out_idx[n0 + i] = (float)mini[i];
        }
    }
}

__global__ __launch_bounds__(256, 2)
void vq_gather_kernel(const float* __restrict__ cb, const float* __restrict__ z,
                      const int* __restrict__ codes, float* __restrict__ out_zq,
                      float* __restrict__ loss)
{
    __shared__ float rows[64 * 257];
    __shared__ int   ks[64];
    __shared__ float wsum[4];
    const int t = threadIdx.x, blk = blockIdx.x;
    const int b = blk >> 4, hw0 = (blk & 15) << 6, n0 = blk << 6;
    if (t < 64) ks[t] = codes[n0 + t];
    __syncthreads();
#pragma unroll 4
    for (int i = 0; i < 64; ++i) rows[i * 257 + t] = cb[(size_t)ks[i] * 256 + t];
    __syncthreads();
    const int dq = t >> 6, hw = t & 63;
    const size_t obase = ((size_t)b << 18) + hw0 + hw;
    float sum = 0.f;
#pragma unroll 4
    for (int dd = 0; dd < 64; ++dd) {
        const int d = (dq << 6) + dd;
        const float  q  = rows[hw * 257 + d];
        const size_t a  = obase + (size_t)d * 1024;
        const float  zv = z[a];
        out_zq[a] = q;
        const float diff = q - zv;
        sum = fmaf(diff, diff, sum);
    }
#pragma unroll
    for (int m = 1; m <= 32; m <<= 1) sum += __shfl_xor(sum, m, 64);
    if ((t & 63) == 0) wsum[t >> 6] = sum;
    __syncthreads();
    if (t == 0) {
        const float s = (wsum[0] + wsum[1]) + (wsum[2] + wsum[3]);
        atomicAdd(loss, s * (1.25f / 8388608.0f));
    }
}

// ---------------------------------------------------------------------------
extern "C" void kernel_launch(void* const* d_in, const int* in_sizes, int n_in,
                              void* d_out, int out_size, void* d_ws, size_t ws_size,
                              hipStream_t stream)
{
    (void)in_sizes; (void)n_in; (void)out_size;

    const float* z  = (const float*)d_in[0];   // 32*256*32*32 fp32
    const float* cb = (const float*)d_in[1];   // 1024*256 fp32

    float* out      = (float*)d_out;
    float* out_zq   = out;                     // 8388608
    float* out_idx  = out + 8388608;           // 32768 (indices as float values)
    float* out_loss = out + 8421376;           // 1

    // MFMA-path workspace: packed(256KB) | z0|z1|z2 (16MB each) | c0|c1|c2 | cnorm
    const size_t NEED = 262144ull + 3ull * 16777216ull + 3ull * 524288ull + 4096ull;

    if (ws_size >= NEED) {
        unsigned long long* packed = (unsigned long long*)d_ws;
        unsigned short* z0 = (unsigned short*)((char*)d_ws + 262144);
        unsigned short* z1 = z0 + 8388608u;
        unsigned short* z2 = z1 + 8388608u;
        unsigned short* c0 = z2 + 8388608u;
        unsigned short* c1 = c0 + 262144u;
        unsigned short* c2 = c1 + 262144u;
        float* cnorm = (float*)(c2 + 262144u);

        hipMemsetAsync(out_loss, 0, sizeof(float), stream);
        hipMemsetAsync(packed, 0xFF, 262144, stream);
        vq_csplit_kernel<<<256, 256, 0, stream>>>(cb, c0, c1, c2);
        vq_cnorm_kernel<<<4, 256, 0, stream>>>(cb, cnorm);
        vq_zsplit_kernel<<<512, 256, 0, stream>>>(z, z0, z1, z2);
        vq_mfma_argmin_kernel<<<512, 512, 0, stream>>>(z0, c0, cnorm, packed);
        vq_gather_packed_kernel<<<512, 256, 0, stream>>>(cb, z, packed, out_zq, out_idx, out_loss);
    } else {
        // fallback: round-3 fp32 path (ws >= 1.38MB known OK)
        float* ctT   = (float*)d_ws;
        float* cnorm = ctT + 256 * 1024;
        int*   codes = (int*)(cnorm + 1024);

        hipMemsetAsync(out_loss, 0, sizeof(float), stream);
        vq_transpose_kernel<<<64, 256, 0, stream>>>(cb, ctT);
        vq_cnorm_kernel<<<4, 256, 0, stream>>>(cb, cnorm);
        vq_argmin_kernel<<<512, 512, 0, stream>>>(z, ctT, cnorm, codes, out_idx);
        vq_gather_kernel<<<512, 256, 0, stream>>>(cb, z, codes, out_zq, out_loss);
    }
}

// Round 11
// 172.635 us; speedup vs baseline: 1.0918x; 1.0918x over previous
//
#include <hip/hip_runtime.h>
#include <cstdint>
#include <cstddef>

// Problem constants (B=32, D=256, H=32, W=32, K=1024), N = B*H*W = 32768.
// MFMA path: fp32 -> 3x bf16 split; 6 concat-K segments -> bf16 GEMM
// M=32768 N=1024 K=1536; error ~ fp32 accumulation (numpy-grade).
//
// History: r5 128² 716TF; r6 deep pipeline REGRESSED; r7 dbuf neutral;
// r8 256²/4-phase counted-vmcnt 124µs (2-way bank conflict); r9 fixed
// swizzle -> 0 conflicts, 114.9µs, MfmaUtil 38%; r10 fat-phase (32 MFMA)
// REGRESSED: needs ~190 VGPR, compiler kept 128 and SPILLED acc
// (WRITE_SIZE 99MB). r11 = r9 structure, but only the 2 correctness-
// required s_barriers per tile (after each vmcnt(4)); the other 6 were
// lockstep alignment only (staging never writes the buffer being read).
// sched_barrier(0)+memory fences kept at the old points to pin codegen.

typedef __attribute__((ext_vector_type(8))) short bf16x8;
typedef __attribute__((ext_vector_type(4))) float f32x4;

#define GL2LDS(g, l) __builtin_amdgcn_global_load_lds( \
    (__attribute__((address_space(1))) const void*)(g), \
    (__attribute__((address_space(3))) void*)(l), 16, 0, 0)

__device__ __forceinline__ unsigned short rne_bf16(float f) {
    unsigned u = __float_as_uint(f);
    return (unsigned short)((u + 0x7FFFu + ((u >> 16) & 1u)) >> 16);
}
__device__ __forceinline__ float bf16_to_f(unsigned short h) {
    return __uint_as_float((unsigned)h << 16);
}

// ---------------------------------------------------------------------------
// codebook row norms ||c_k||^2
// ---------------------------------------------------------------------------
__global__ __launch_bounds__(256)
void vq_cnorm_kernel(const float* __restrict__ cb, float* __restrict__ cnorm)
{
    const int k = blockIdx.x * 256 + threadIdx.x;  // grid=4
    const float4* row = reinterpret_cast<const float4*>(cb + (size_t)k * 256);
    float s0 = 0.f, s1 = 0.f, s2 = 0.f, s3 = 0.f;
#pragma unroll 8
    for (int i = 0; i < 64; ++i) {
        float4 v = row[i];
        s0 = fmaf(v.x, v.x, s0);
        s1 = fmaf(v.y, v.y, s1);
        s2 = fmaf(v.z, v.z, s2);
        s3 = fmaf(v.w, v.w, s3);
    }
    cnorm[k] = (s0 + s1) + (s2 + s3);
}

// ---------------------------------------------------------------------------
// codebook split: [1024][256] fp32 -> c0,c1,c2 bf16
// ---------------------------------------------------------------------------
__global__ __launch_bounds__(256)
void vq_csplit_kernel(const float* __restrict__ cb, unsigned short* __restrict__ c0,
                      unsigned short* __restrict__ c1, unsigned short* __restrict__ c2)
{
    const int idx = blockIdx.x * 256 + threadIdx.x;   // grid 256
    float4 v = reinterpret_cast<const float4*>(cb)[idx];
    float f[4] = { v.x, v.y, v.z, v.w };
    ushort4 h0, h1, h2;
    unsigned short* p0[4] = { &h0.x, &h0.y, &h0.z, &h0.w };
    unsigned short* p1[4] = { &h1.x, &h1.y, &h1.z, &h1.w };
    unsigned short* p2[4] = { &h2.x, &h2.y, &h2.z, &h2.w };
#pragma unroll
    for (int j = 0; j < 4; ++j) {
        unsigned short b0 = rne_bf16(f[j]); float r1 = f[j] - bf16_to_f(b0);
        unsigned short b1 = rne_bf16(r1);   float r2 = r1 - bf16_to_f(b1);
        unsigned short b2 = rne_bf16(r2);
        *p0[j] = b0; *p1[j] = b1; *p2[j] = b2;
    }
    reinterpret_cast<ushort4*>(c0)[idx] = h0;
    reinterpret_cast<ushort4*>(c1)[idx] = h1;
    reinterpret_cast<ushort4*>(c2)[idx] = h2;
}

// ---------------------------------------------------------------------------
// z split+transpose: z[b][d][hw] fp32 -> z0,z1,z2 bf16 [n][d]
// ---------------------------------------------------------------------------
__global__ __launch_bounds__(256)
void vq_zsplit_kernel(const float* __restrict__ z, unsigned short* __restrict__ z0,
                      unsigned short* __restrict__ z1, unsigned short* __restrict__ z2)
{
    __shared__ float zl[64 * 264];
    const int t = threadIdx.x, blk = blockIdx.x;        // 512 blocks
    const int b = blk >> 4, hw0 = (blk & 15) << 6;
    const float* zb = z + ((size_t)b << 18) + hw0;
#pragma unroll 8
    for (int i = 0; i < 64; ++i) {
        int idx = i * 256 + t;
        int d = idx >> 6, hwl = idx & 63;
        zl[hwl * 264 + d] = zb[(size_t)d * 1024 + hwl];
    }
    __syncthreads();
    const int n0 = (b << 10) + hw0;
#pragma unroll
    for (int p = 0; p < 8; ++p) {
        const int hwl = p * 8 + (t >> 5);
        const int d0 = (t & 31) * 8;
        const float* src = &zl[hwl * 264 + d0];
        unsigned short h0[8], h1[8], h2[8];
#pragma unroll
        for (int j = 0; j < 8; ++j) {
            float f = src[j];
            unsigned short b0 = rne_bf16(f);  float r1 = f - bf16_to_f(b0);
            unsigned short b1 = rne_bf16(r1); float r2 = r1 - bf16_to_f(b1);
            unsigned short b2 = rne_bf16(r2);
            h0[j] = b0; h1[j] = b1; h2[j] = b2;
        }
        const size_t o = (size_t)(n0 + hwl) * 256 + d0;
        ushort4 a;
        a = ushort4{h0[0],h0[1],h0[2],h0[3]}; *reinterpret_cast<ushort4*>(z0 + o)     = a;
        a = ushort4{h0[4],h0[5],h0[6],h0[7]}; *reinterpret_cast<ushort4*>(z0 + o + 4) = a;
        a = ushort4{h1[0],h1[1],h1[2],h1[3]}; *reinterpret_cast<ushort4*>(z1 + o)     = a;
        a = ushort4{h1[4],h1[5],h1[6],h1[7]}; *reinterpret_cast<ushort4*>(z1 + o + 4) = a;
        a = ushort4{h2[0],h2[1],h2[2],h2[3]}; *reinterpret_cast<ushort4*>(z2 + o)     = a;
        a = ushort4{h2[4],h2[5],h2[6],h2[7]}; *reinterpret_cast<ushort4*>(z2 + o + 4) = a;
    }
}

// ---------------------------------------------------------------------------
// MFMA GEMM + fused argmin — 256² tile, 8 waves, 4 thin phases/K-tile,
// counted vmcnt, MINIMAL barriers (2/tile).
//
// LDS: Ld[buf2][mat2][kk2][256x32] bf16 = 128KB (1 block/CU, 8 waves).
// Phase (t,mh,kk): ds_read 4 A-frags (+4 B at mh==0) -> stage one plane of
// t+1 into buf^1 -> fence -> setprio(1) 16 MFMA setprio(0) -> [vmcnt] ->
// fence/barrier. Hazards: staging writes buf^1, never buf -> NO intra-tile
// hazard; the ONLY cross-wave syncs needed are after the two vmcnt(4)
// points (kk-plane data staged by other waves). r9's other 6 barriers/tile
// were alignment only -- replaced by sched_barrier(0)+memory fences to keep
// codegen (and VGPR pressure, 124) pinned. vmcnt ledger identical to r9.
//
// Swizzle (r9-proven, 0 conflicts): bank = (row&1)*16 + slot*4; store chunk
// c of row r at slot c ^ ((r>>1)&3); gl2lds writes linearly -> GLOBAL source
// chunk pre-swizzled (selem), ds_read applies same XOR (fco).
// Accumulation order identical to r9 -> bit-identical distances.
// ---------------------------------------------------------------------------
__global__ __launch_bounds__(512, 2)
void vq_mfma_argmin_kernel(const unsigned short* __restrict__ zp,
                           const unsigned short* __restrict__ cp,
                           const float* __restrict__ cnorm,
                           unsigned long long* __restrict__ packed)
{
    __shared__ unsigned short Ld[2][2][2][256 * 32];   // 128KB

    const int tid = threadIdx.x, l = tid & 63, w = tid >> 6;
    const int wr = w >> 2, wc = w & 3;                 // 2 x 4 wave grid
    const int nid = ((blockIdx.x & 7) << 6) | (blockIdx.x >> 3);  // XCD swizzle (512%8==0)
    const int bm = nid >> 2, bn = nid & 3;             // 128 x 4 tiles
    const int arow = bm * 256, brow = bn * 256;

    f32x4 acc[8][4];
#pragma unroll
    for (int m = 0; m < 8; ++m)
#pragma unroll
        for (int n = 0; n < 4; ++n) acc[m][n] = f32x4{0.f, 0.f, 0.f, 0.f};

    // staging lane geometry: lane l -> row l>>2, slot l&3; source chunk
    // pre-swizzled by row bits 1-2 ((l>>3)&3) so stored slot = c ^ ((r>>1)&3)
    const int srow  = l >> 2;
    const int selem = (((l & 3) ^ ((l >> 3) & 3))) << 3;

    // fragment-read: chunk hi4 of row r at slot hi4 ^ ((r>>1)&3); r ≡ lo16 (16)
    const int lo16 = l & 15, hi4 = l >> 4;
    const int fco = ((hi4 ^ ((lo16 >> 1) & 3))) << 3;

    // segment tables packed as nibbles: A {0,1,2,0,1,0}, B {0,0,0,1,1,2}
#define STAGE(tt, mat, kk) do {                                               \
    const int seg_ = (tt) >> 2;                                               \
    const unsigned short* S_ = (mat)                                          \
        ? cp + (size_t)((0x211000 >> (seg_ << 2)) & 3) * 262144u              \
        : zp + (size_t)((0x010210 >> (seg_ << 2)) & 3) * 8388608u;            \
    const int R_  = (mat) ? brow : arow;                                      \
    const int KO_ = (((tt) & 3) << 6) + ((kk) << 5) + selem;                  \
    GL2LDS(S_ + (size_t)(R_ + (w * 2 + 0) * 16 + srow) * 256 + KO_,           \
           &Ld[(tt) & 1][mat][kk][(w * 2 + 0) * 512]);                        \
    GL2LDS(S_ + (size_t)(R_ + (w * 2 + 1) * 16 + srow) * 256 + KO_,           \
           &Ld[(tt) & 1][mat][kk][(w * 2 + 1) * 512]);                        \
} while (0)

#define VM4  asm volatile("s_waitcnt vmcnt(4)"  ::: "memory")
#define VM0  asm volatile("s_waitcnt vmcnt(0)"  ::: "memory")
#define NOPS ((void)0)
#define FNCE do { asm volatile("" ::: "memory");                              \
                  __builtin_amdgcn_sched_barrier(0); } while (0)
#define SBAR do { asm volatile("" ::: "memory");                              \
                  __builtin_amdgcn_s_barrier();                               \
                  __builtin_amdgcn_sched_barrier(0); } while (0)

    bf16x8 bfr0, bfr1, bfr2, bfr3;   // B frags, loaded at mh==0, reused mh==1

#define PH(t, mh, kk, STAGESTMT, VMSTMT, BARSTMT) do {                        \
    const unsigned short* Ap_ = &Ld[(t) & 1][0][kk][0];                       \
    const unsigned short* Bp_ = &Ld[(t) & 1][1][kk][0];                       \
    bf16x8 a0, a1, a2, a3;                                                    \
    a0 = *(const bf16x8*)&Ap_[(wr*128 + ((mh)*4+0)*16 + lo16)*32 + fco];      \
    a1 = *(const bf16x8*)&Ap_[(wr*128 + ((mh)*4+1)*16 + lo16)*32 + fco];      \
    a2 = *(const bf16x8*)&Ap_[(wr*128 + ((mh)*4+2)*16 + lo16)*32 + fco];      \
    a3 = *(const bf16x8*)&Ap_[(wr*128 + ((mh)*4+3)*16 + lo16)*32 + fco];      \
    if ((mh) == 0) {                                                          \
        bfr0 = *(const bf16x8*)&Bp_[(wc*64 + 0*16 + lo16)*32 + fco];          \
        bfr1 = *(const bf16x8*)&Bp_[(wc*64 + 1*16 + lo16)*32 + fco];          \
        bfr2 = *(const bf16x8*)&Bp_[(wc*64 + 2*16 + lo16)*32 + fco];          \
        bfr3 = *(const bf16x8*)&Bp_[(wc*64 + 3*16 + lo16)*32 + fco];          \
    }                                                                         \
    STAGESTMT;                                                                \
    FNCE;                                                                     \
    __builtin_amdgcn_s_setprio(1);                                            \
    acc[(mh)*4+0][0] = __builtin_amdgcn_mfma_f32_16x16x32_bf16(a0, bfr0, acc[(mh)*4+0][0], 0,0,0); \
    acc[(mh)*4+0][1] = __builtin_amdgcn_mfma_f32_16x16x32_bf16(a0, bfr1, acc[(mh)*4+0][1], 0,0,0); \
    acc[(mh)*4+0][2] = __builtin_amdgcn_mfma_f32_16x16x32_bf16(a0, bfr2, acc[(mh)*4+0][2], 0,0,0); \
    acc[(mh)*4+0][3] = __builtin_amdgcn_mfma_f32_16x16x32_bf16(a0, bfr3, acc[(mh)*4+0][3], 0,0,0); \
    acc[(mh)*4+1][0] = __builtin_amdgcn_mfma_f32_16x16x32_bf16(a1, bfr0, acc[(mh)*4+1][0], 0,0,0); \
    acc[(mh)*4+1][1] = __builtin_amdgcn_mfma_f32_16x16x32_bf16(a1, bfr1, acc[(mh)*4+1][1], 0,0,0); \
    acc[(mh)*4+1][2] = __builtin_amdgcn_mfma_f32_16x16x32_bf16(a1, bfr2, acc[(mh)*4+1][2], 0,0,0); \
    acc[(mh)*4+1][3] = __builtin_amdgcn_mfma_f32_16x16x32_bf16(a1, bfr3, acc[(mh)*4+1][3], 0,0,0); \
    acc[(mh)*4+2][0] = __builtin_amdgcn_mfma_f32_16x16x32_bf16(a2, bfr0, acc[(mh)*4+2][0], 0,0,0); \
    acc[(mh)*4+2][1] = __builtin_amdgcn_mfma_f32_16x16x32_bf16(a2, bfr1, acc[(mh)*4+2][1], 0,0,0); \
    acc[(mh)*4+2][2] = __builtin_amdgcn_mfma_f32_16x16x32_bf16(a2, bfr2, acc[(mh)*4+2][2], 0,0,0); \
    acc[(mh)*4+2][3] = __builtin_amdgcn_mfma_f32_16x16x32_bf16(a2, bfr3, acc[(mh)*4+2][3], 0,0,0); \
    acc[(mh)*4+3][0] = __builtin_amdgcn_mfma_f32_16x16x32_bf16(a3, bfr0, acc[(mh)*4+3][0], 0,0,0); \
    acc[(mh)*4+3][1] = __builtin_amdgcn_mfma_f32_16x16x32_bf16(a3, bfr1, acc[(mh)*4+3][1], 0,0,0); \
    acc[(mh)*4+3][2] = __builtin_amdgcn_mfma_f32_16x16x32_bf16(a3, bfr2, acc[(mh)*4+3][2], 0,0,0); \
    acc[(mh)*4+3][3] = __builtin_amdgcn_mfma_f32_16x16x32_bf16(a3, bfr3, acc[(mh)*4+3][3], 0,0,0); \
    __builtin_amdgcn_s_setprio(0);                                            \
    VMSTMT;                                                                   \
    BARSTMT;                                                                  \
} while (0)

    // barriers ONLY after the two vmcnt points (cross-wave staging sync)
#define TILE(t, SA0, SB0, SA1, SB1, V2, V4)                                   \
    PH(t, 0, 0, SA0, NOPS, FNCE);                                             \
    PH(t, 1, 0, SB0, V2,   SBAR);                                             \
    PH(t, 0, 1, SA1, NOPS, FNCE);                                             \
    PH(t, 1, 1, SB1, V4,   SBAR)

    // prologue: stage tile 0 fully; wait its kk0 (leave kk1's 4); barrier
    STAGE(0, 0, 0); STAGE(0, 1, 0); STAGE(0, 0, 1); STAGE(0, 1, 1);
    VM4;
    SBAR;

#pragma unroll 2
    for (int t = 0; t <= 22; ++t) {
        TILE(t, STAGE(t + 1, 0, 0), STAGE(t + 1, 1, 0),
                STAGE(t + 1, 0, 1), STAGE(t + 1, 1, 1), VM4, VM4);
    }
    TILE(23, NOPS, NOPS, NOPS, NOPS, VM0, NOPS);

#undef TILE
#undef PH
#undef STAGE

    // epilogue: fused argmin. col = brow + wc*64 + n*16 + lo16
    int coln[4]; float cnv[4];
#pragma unroll
    for (int n = 0; n < 4; ++n) {
        coln[n] = brow + wc * 64 + n * 16 + lo16;
        cnv[n] = cnorm[coln[n]];
    }
#pragma unroll
    for (int m = 0; m < 8; ++m) {
#pragma unroll
        for (int j = 0; j < 4; ++j) {
            unsigned long long best = 0xFFFFFFFFFFFFFFFFull;
#pragma unroll
            for (int n = 0; n < 4; ++n) {
                float d = fmaf(-2.0f, acc[m][n][j], cnv[n]);
                unsigned u = __float_as_uint(d);
                u = (u & 0x80000000u) ? ~u : (u | 0x80000000u);   // order-preserving map
                unsigned long long pk = ((unsigned long long)u << 32) | (unsigned)coln[n];
                best = pk < best ? pk : best;
            }
#pragma unroll
            for (int mask = 1; mask <= 8; mask <<= 1) {
                unsigned long long o = __shfl_xor(best, mask, 64);
                best = o < best ? o : best;
            }
            if (lo16 == 0) {
                const int row = arow + wr * 128 + m * 16 + hi4 * 4 + j;
                atomicMin(&packed[row], best);
            }
        }
    }
}

// ---------------------------------------------------------------------------
// gather (packed): z_q write, out_idx write, vq_loss accumulate
// ---------------------------------------------------------------------------
__global__ __launch_bounds__(256, 2)
void vq_gather_packed_kernel(const float* __restrict__ cb, const float* __restrict__ z,
                             const unsigned long long* __restrict__ packed,
                             float* __restrict__ out_zq, float* __restrict__ out_idx,
                             float* __restrict__ loss)
{
    __shared__ float rows[64 * 257];
    __shared__ int   ks[64];
    __shared__ float wsum[4];

    const int t   = threadIdx.x;
    const int blk = blockIdx.x;            // 512 blocks
    const int b   = blk >> 4;
    const int hw0 = (blk & 15) << 6;
    const int n0  = blk << 6;

    if (t < 64) {
        const int k = (int)(packed[n0 + t] & 0xFFFFFFFFull);
        ks[t] = k;
        out_idx[n0 + t] = (float)k;
    }
    __syncthreads();

#pragma unroll 4
    for (int i = 0; i < 64; ++i) {
        rows[i * 257 + t] = cb[(size_t)ks[i] * 256 + t];
    }
    __syncthreads();

    const int dq = t >> 6;
    const int hw = t & 63;
    const size_t obase = ((size_t)b << 18) + hw0 + hw;
    float sum = 0.f;
#pragma unroll 4
    for (int dd = 0; dd < 64; ++dd) {
        const int d = (dq << 6) + dd;
        const float  q  = rows[hw * 257 + d];
        const size_t a  = obase + (size_t)d * 1024;
        const float  zv = z[a];
        out_zq[a] = q;
        const float diff = q - zv;
        sum = fmaf(diff, diff, sum);
    }
#pragma unroll
    for (int m = 1; m <= 32; m <<= 1) sum += __shfl_xor(sum, m, 64);
    if ((t & 63) == 0) wsum[t >> 6] = sum;
    __syncthreads();
    if (t == 0) {
        const float s = (wsum[0] + wsum[1]) + (wsum[2] + wsum[3]);
        atomicAdd(loss, s * (1.25f / 8388608.0f));   // (1+0.25)*SSE/(B*D*H*W)
    }
}

// ===========================================================================
// FALLBACK PATH (ws too small): round-3 fp32 VALU kernels, known-passing.
// ===========================================================================
__global__ __launch_bounds__(256)
void vq_transpose_kernel(const float* __restrict__ cb, float* __restrict__ ctT)
{
    __shared__ float tile[64 * 65];
    const int t  = threadIdx.x;
    const int kb = blockIdx.x >> 2, db = blockIdx.x & 3;
    const int k0 = kb << 6, d0 = db << 6;
#pragma unroll
    for (int i = 0; i < 16; ++i) {
        int idx = i * 256 + t;
        int r = idx >> 6, c = idx & 63;
        tile[r * 65 + c] = cb[(size_t)(k0 + r) * 256 + d0 + c];
    }
    __syncthreads();
#pragma unroll
    for (int i = 0; i < 16; ++i) {
        int idx = i * 256 + t;
        int r = idx >> 6, c = idx & 63;
        ctT[(size_t)(d0 + r) * 1024 + k0 + c] = tile[c * 65 + r];
    }
}

__global__ __launch_bounds__(512, 2)
void vq_argmin_kernel(const float* __restrict__ z, const float* __restrict__ ctT,
                      const float* __restrict__ cnorm, int* __restrict__ codes,
                      float* __restrict__ out_idx)
{
    __shared__ float zt[256 * 64];
    __shared__ float ct[16 * 256];
    const int t = threadIdx.x, tx = t & 63, ty = t >> 6, p0 = ty << 3;
    const int blk = blockIdx.x, b = blk >> 4, hw0 = (blk & 15) << 6;
    const float* zbase = z + ((size_t)b << 18) + hw0;
#pragma unroll
    for (int i = 0; i < 8; ++i) {
        int idx = i * 512 + t;
        int d = idx >> 4, c4 = (idx & 15) << 2;
        float4 v = *reinterpret_cast<const float4*>(zbase + (size_t)d * 1024 + c4);
        *reinterpret_cast<float4*>(&zt[d * 64 + c4]) = v;
    }
    float minv[8]; int mini[8];
#pragma unroll
    for (int i = 0; i < 8; ++i) { minv[i] = 3.0e38f; mini[i] = 0; }
    const float* zrd = &zt[p0];
    const float* crd = &ct[tx << 2];
    for (int kt = 0; kt < 4; ++kt) {
        const int k0 = kt << 8;
        float acc[8][4];
#pragma unroll
        for (int i = 0; i < 8; ++i)
#pragma unroll
            for (int j = 0; j < 4; ++j) acc[i][j] = 0.f;
        for (int dc = 0; dc < 16; ++dc) {
            const int d0 = dc << 4;
            __syncthreads();
#pragma unroll
            for (int i = 0; i < 2; ++i) {
                int idx = i * 512 + t;
                int r = idx >> 6, c4 = (idx & 63) << 2;
                float4 v = *reinterpret_cast<const float4*>(ctT + (size_t)(d0 + r) * 1024 + k0 + c4);
                *reinterpret_cast<float4*>(&ct[r * 256 + c4]) = v;
            }
            __syncthreads();
            const float* zp = zrd + d0 * 64;
#pragma unroll
            for (int d = 0; d < 16; ++d) {
                float4 za = *reinterpret_cast<const float4*>(zp + d * 64);
                float4 zb = *reinterpret_cast<const float4*>(zp + d * 64 + 4);
                float4 cc = *reinterpret_cast<const float4*>(crd + d * 256);
#define VQ_FMA_ROW(ii, zv)                          \
                acc[ii][0] = fmaf(zv, cc.x, acc[ii][0]); \
                acc[ii][1] = fmaf(zv, cc.y, acc[ii][1]); \
                acc[ii][2] = fmaf(zv, cc.z, acc[ii][2]); \
                acc[ii][3] = fmaf(zv, cc.w, acc[ii][3]);
                VQ_FMA_ROW(0, za.x) VQ_FMA_ROW(1, za.y) VQ_FMA_ROW(2, za.z) VQ_FMA_ROW(3, za.w)
                VQ_FMA_ROW(4, zb.x) VQ_FMA_ROW(5, zb.y) VQ_FMA_ROW(6, zb.z) VQ_FMA_ROW(7, zb.w)
#undef VQ_FMA_ROW
            }
        }
#pragma unroll
        for (int j = 0; j < 4; ++j) {
            const int k = k0 + (tx << 2) + j;
            const float cn = cnorm[k];
#pragma unroll
            for (int i = 0; i < 8; ++i) {
                float dist = fmaf(-2.0f, acc[i][j], cn);
                if (dist < minv[i]) { minv[i] = dist; mini[i] = k; }
            }
        }
    }
#pragma unroll
    for (int m = 1; m <= 32; m <<= 1) {
#pragma unroll
        for (int i = 0; i < 8; ++i) {
            float ov = __shfl_xor(minv[i], m, 64);
            int   oi = __shfl_xor(mini[i], m, 64);
            if (ov < minv[i] || (ov == minv[i] && oi < mini[i])) { minv[i] = ov; mini[i] = oi; }
        }
    }
    if (tx == 0) {
        const int n0 = (blk << 6) + p0;
#pragma unroll
        for (int i = 0; i < 8; ++i) {
            codes[n0 + i]   = mini[i];
            out_idx[n0 + i] = (float)mini[i];
        }
    }
}

__global__ __launch_bounds__(256, 2)
void vq_gather_kernel(const float* __restrict__ cb, const float* __restrict__ z,
                      const int* __restrict__ codes, float* __restrict__ out_zq,
                      float* __restrict__ loss)
{
    __shared__ float rows[64 * 257];
    __shared__ int   ks[64];
    __shared__ float wsum[4];
    const int t = threadIdx.x, blk = blockIdx.x;
    const int b = blk >> 4, hw0 = (blk & 15) << 6, n0 = blk << 6;
    if (t < 64) ks[t] = codes[n0 + t];
    __syncthreads();
#pragma unroll 4
    for (int i = 0; i < 64; ++i) rows[i * 257 + t] = cb[(size_t)ks[i] * 256 + t];
    __syncthreads();
    const int dq = t >> 6, hw = t & 63;
    const size_t obase = ((size_t)b << 18) + hw0 + hw;
    float sum = 0.f;
#pragma unroll 4
    for (int dd = 0; dd < 64; ++dd) {
        const int d = (dq << 6) + dd;
        const float  q  = rows[hw * 257 + d];
        const size_t a  = obase + (size_t)d * 1024;
        const float  zv = z[a];
        out_zq[a] = q;
        const float diff = q - zv;
        sum = fmaf(diff, diff, sum);
    }
#pragma unroll
    for (int m = 1; m <= 32; m <<= 1) sum += __shfl_xor(sum, m, 64);
    if ((t & 63) == 0) wsum[t >> 6] = sum;
    __syncthreads();
    if (t == 0) {
        const float s = (wsum[0] + wsum[1]) + (wsum[2] + wsum[3]);
        atomicAdd(loss, s * (1.25f / 8388608.0f));
    }
}

// ---------------------------------------------------------------------------
extern "C" void kernel_launch(void* const* d_in, const int* in_sizes, int n_in,
                              void* d_out, int out_size, void* d_ws, size_t ws_size,
                              hipStream_t stream)
{
    (void)in_sizes; (void)n_in; (void)out_size;

    const float* z  = (const float*)d_in[0];   // 32*256*32*32 fp32
    const float* cb = (const float*)d_in[1];   // 1024*256 fp32

    float* out      = (float*)d_out;
    float* out_zq   = out;                     // 8388608
    float* out_idx  = out + 8388608;           // 32768 (indices as float values)
    float* out_loss = out + 8421376;           // 1

    // MFMA-path workspace: packed(256KB) | z0|z1|z2 (16MB each) | c0|c1|c2 | cnorm
    const size_t NEED = 262144ull + 3ull * 16777216ull + 3ull * 524288ull + 4096ull;

    if (ws_size >= NEED) {
        unsigned long long* packed = (unsigned long long*)d_ws;
        unsigned short* z0 = (unsigned short*)((char*)d_ws + 262144);
        unsigned short* z1 = z0 + 8388608u;
        unsigned short* z2 = z1 + 8388608u;
        unsigned short* c0 = z2 + 8388608u;
        unsigned short* c1 = c0 + 262144u;
        unsigned short* c2 = c1 + 262144u;
        float* cnorm = (float*)(c2 + 262144u);

        hipMemsetAsync(out_loss, 0, sizeof(float), stream);
        hipMemsetAsync(packed, 0xFF, 262144, stream);
        vq_csplit_kernel<<<256, 256, 0, stream>>>(cb, c0, c1, c2);
        vq_cnorm_kernel<<<4, 256, 0, stream>>>(cb, cnorm);
        vq_zsplit_kernel<<<512, 256, 0, stream>>>(z, z0, z1, z2);
        vq_mfma_argmin_kernel<<<512, 512, 0, stream>>>(z0, c0, cnorm, packed);
        vq_gather_packed_kernel<<<512, 256, 0, stream>>>(cb, z, packed, out_zq, out_idx, out_loss);
    } else {
        // fallback: round-3 fp32 path (ws >= 1.38MB known OK)
        float* ctT   = (float*)d_ws;
        float* cnorm = ctT + 256 * 1024;
        int*   codes = (int*)(cnorm + 1024);

        hipMemsetAsync(out_loss, 0, sizeof(float), stream);
        vq_transpose_kernel<<<64, 256, 0, stream>>>(cb, ctT);
        vq_cnorm_kernel<<<4, 256, 0, stream>>>(cb, cnorm);
        vq_argmin_kernel<<<512, 512, 0, stream>>>(z, ctT, cnorm, codes, out_idx);
        vq_gather_kernel<<<512, 256, 0, stream>>>(cb, z, codes, out_zq, out_loss);
    }
}

// Round 12
// 172.220 us; speedup vs baseline: 1.0945x; 1.0024x over previous
//
#include <hip/hip_runtime.h>
#include <cstdint>
#include <cstddef>

// Problem constants (B=32, D=256, H=32, W=32, K=1024), N = B*H*W = 32768.
// MFMA path: fp32 -> 3x bf16 split; 6 concat-K segments -> bf16 GEMM
// M=32768 N=1024 K=1536; error ~ fp32 accumulation (numpy-grade).
//
// History: r5 128² 716TF; r6 deep pipeline REGRESSED; r7 dbuf neutral;
// r8 256²/4-phase counted-vmcnt 124µs; r9 fixed swizzle -> 0 conflicts,
// 114.9µs (897 TF), MfmaUtil 38% = CURRENT BEST. r10 fat-phase SPILLED
// (needs ~190 VGPR, cap 128). r11 barrier-cut SPILLED too (FETCH +70MB):
// the bfr0-3 B-frags held across P1->P2 became a cross-region live range
// once barriers stopped splitting scheduler regions. r12 = r11 despilled:
// B-frags PHASE-LOCAL (each phase reads its own 4; +8 redundant ds_read/
// tile), barriers 2/tile (only the post-vmcnt correctness points). This is
// the clean test of the lockstep theory (waves drift -> reads hide under
// other waves' MFMAs). Accumulation order unchanged -> bit-identical.

typedef __attribute__((ext_vector_type(8))) short bf16x8;
typedef __attribute__((ext_vector_type(4))) float f32x4;

#define GL2LDS(g, l) __builtin_amdgcn_global_load_lds( \
    (__attribute__((address_space(1))) const void*)(g), \
    (__attribute__((address_space(3))) void*)(l), 16, 0, 0)

__device__ __forceinline__ unsigned short rne_bf16(float f) {
    unsigned u = __float_as_uint(f);
    return (unsigned short)((u + 0x7FFFu + ((u >> 16) & 1u)) >> 16);
}
__device__ __forceinline__ float bf16_to_f(unsigned short h) {
    return __uint_as_float((unsigned)h << 16);
}

// ---------------------------------------------------------------------------
// codebook row norms ||c_k||^2  (summation order feeds argmin -- unchanged)
// ---------------------------------------------------------------------------
__global__ __launch_bounds__(256)
void vq_cnorm_kernel(const float* __restrict__ cb, float* __restrict__ cnorm)
{
    const int k = blockIdx.x * 256 + threadIdx.x;  // grid=4
    const float4* row = reinterpret_cast<const float4*>(cb + (size_t)k * 256);
    float s0 = 0.f, s1 = 0.f, s2 = 0.f, s3 = 0.f;
#pragma unroll 8
    for (int i = 0; i < 64; ++i) {
        float4 v = row[i];
        s0 = fmaf(v.x, v.x, s0);
        s1 = fmaf(v.y, v.y, s1);
        s2 = fmaf(v.z, v.z, s2);
        s3 = fmaf(v.w, v.w, s3);
    }
    cnorm[k] = (s0 + s1) + (s2 + s3);
}

// ---------------------------------------------------------------------------
// codebook split + packed/loss init (memset fusion): grid 256
// ---------------------------------------------------------------------------
__global__ __launch_bounds__(256)
void vq_csplit_kernel(const float* __restrict__ cb, unsigned short* __restrict__ c0,
                      unsigned short* __restrict__ c1, unsigned short* __restrict__ c2,
                      unsigned long long* __restrict__ packed, float* __restrict__ loss)
{
    const int b = blockIdx.x, t = threadIdx.x;
    const int idx = b * 256 + t;
    // fused init (replaces two hipMemsetAsync dispatches)
    if (t < 128) packed[b * 128 + t] = 0xFFFFFFFFFFFFFFFFull;
    if (b == 0 && t == 255) *loss = 0.f;

    float4 v = reinterpret_cast<const float4*>(cb)[idx];
    float f[4] = { v.x, v.y, v.z, v.w };
    ushort4 h0, h1, h2;
    unsigned short* p0[4] = { &h0.x, &h0.y, &h0.z, &h0.w };
    unsigned short* p1[4] = { &h1.x, &h1.y, &h1.z, &h1.w };
    unsigned short* p2[4] = { &h2.x, &h2.y, &h2.z, &h2.w };
#pragma unroll
    for (int j = 0; j < 4; ++j) {
        unsigned short b0 = rne_bf16(f[j]); float r1 = f[j] - bf16_to_f(b0);
        unsigned short b1 = rne_bf16(r1);   float r2 = r1 - bf16_to_f(b1);
        unsigned short b2 = rne_bf16(r2);
        *p0[j] = b0; *p1[j] = b1; *p2[j] = b2;
    }
    reinterpret_cast<ushort4*>(c0)[idx] = h0;
    reinterpret_cast<ushort4*>(c1)[idx] = h1;
    reinterpret_cast<ushort4*>(c2)[idx] = h2;
}

// ---------------------------------------------------------------------------
// z split+transpose: z[b][d][hw] fp32 -> z0,z1,z2 bf16 [n][d]
// ---------------------------------------------------------------------------
__global__ __launch_bounds__(256)
void vq_zsplit_kernel(const float* __restrict__ z, unsigned short* __restrict__ z0,
                      unsigned short* __restrict__ z1, unsigned short* __restrict__ z2)
{
    __shared__ float zl[64 * 264];
    const int t = threadIdx.x, blk = blockIdx.x;        // 512 blocks
    const int b = blk >> 4, hw0 = (blk & 15) << 6;
    const float* zb = z + ((size_t)b << 18) + hw0;
#pragma unroll 8
    for (int i = 0; i < 64; ++i) {
        int idx = i * 256 + t;
        int d = idx >> 6, hwl = idx & 63;
        zl[hwl * 264 + d] = zb[(size_t)d * 1024 + hwl];
    }
    __syncthreads();
    const int n0 = (b << 10) + hw0;
#pragma unroll
    for (int p = 0; p < 8; ++p) {
        const int hwl = p * 8 + (t >> 5);
        const int d0 = (t & 31) * 8;
        const float* src = &zl[hwl * 264 + d0];
        unsigned short h0[8], h1[8], h2[8];
#pragma unroll
        for (int j = 0; j < 8; ++j) {
            float f = src[j];
            unsigned short b0 = rne_bf16(f);  float r1 = f - bf16_to_f(b0);
            unsigned short b1 = rne_bf16(r1); float r2 = r1 - bf16_to_f(b1);
            unsigned short b2 = rne_bf16(r2);
            h0[j] = b0; h1[j] = b1; h2[j] = b2;
        }
        const size_t o = (size_t)(n0 + hwl) * 256 + d0;
        ushort4 a;
        a = ushort4{h0[0],h0[1],h0[2],h0[3]}; *reinterpret_cast<ushort4*>(z0 + o)     = a;
        a = ushort4{h0[4],h0[5],h0[6],h0[7]}; *reinterpret_cast<ushort4*>(z0 + o + 4) = a;
        a = ushort4{h1[0],h1[1],h1[2],h1[3]}; *reinterpret_cast<ushort4*>(z1 + o)     = a;
        a = ushort4{h1[4],h1[5],h1[6],h1[7]}; *reinterpret_cast<ushort4*>(z1 + o + 4) = a;
        a = ushort4{h2[0],h2[1],h2[2],h2[3]}; *reinterpret_cast<ushort4*>(z2 + o)     = a;
        a = ushort4{h2[4],h2[5],h2[6],h2[7]}; *reinterpret_cast<ushort4*>(z2 + o + 4) = a;
    }
}

// ---------------------------------------------------------------------------
// MFMA GEMM + fused argmin — 256² tile, 8 waves, 4 thin phases/K-tile,
// counted vmcnt, 2 barriers/tile, PHASE-LOCAL fragments (spill-proof).
//
// LDS: Ld[buf2][mat2][kk2][256x32] bf16 = 128KB (1 block/CU, 8 waves).
// Phase (t,mh,kk): ds_read 4 A-frags + 4 B-frags (phase-local; B re-read at
// mh==1 -- +8 reads/tile, kills the r11 cross-phase live range) -> stage one
// plane of t+1 into buf^1 -> fence -> setprio(1) 16 MFMA setprio(0) ->
// [vmcnt] -> fence/barrier.
// Correctness barriers (hazard ledger): kh0 planes of t are guaranteed by
// t-1's P4-end vmcnt(4)+SBAR; kh1 planes by t's P2-end vmcnt(4)+SBAR. The
// other 6 r9 barriers were lockstep alignment; removing them lets waves
// drift <=2 phases so reads hide under other waves' MFMAs. STAGE always
// writes buf^1 which nobody reads during tile t -> no intra-tile hazard.
// vmcnt is per-wave; each wave issues its own 4 loads/tile in program
// order, so the ledger is drift-independent.
//
// Swizzle (r9-proven, 0 conflicts): bank = (row&1)*16 + slot*4; store chunk
// c of row r at slot c ^ ((r>>1)&3); gl2lds writes linearly -> GLOBAL source
// chunk pre-swizzled (selem), ds_read applies same XOR (fco).
// Accumulation order identical to r9 -> bit-identical distances.
// ---------------------------------------------------------------------------
__global__ __launch_bounds__(512, 2)
void vq_mfma_argmin_kernel(const unsigned short* __restrict__ zp,
                           const unsigned short* __restrict__ cp,
                           const float* __restrict__ cnorm,
                           unsigned long long* __restrict__ packed)
{
    __shared__ unsigned short Ld[2][2][2][256 * 32];   // 128KB

    const int tid = threadIdx.x, l = tid & 63, w = tid >> 6;
    const int wr = w >> 2, wc = w & 3;                 // 2 x 4 wave grid
    const int nid = ((blockIdx.x & 7) << 6) | (blockIdx.x >> 3);  // XCD swizzle (512%8==0)
    const int bm = nid >> 2, bn = nid & 3;             // 128 x 4 tiles
    const int arow = bm * 256, brow = bn * 256;

    f32x4 acc[8][4];
#pragma unroll
    for (int m = 0; m < 8; ++m)
#pragma unroll
        for (int n = 0; n < 4; ++n) acc[m][n] = f32x4{0.f, 0.f, 0.f, 0.f};

    // staging lane geometry: lane l -> row l>>2, slot l&3; source chunk
    // pre-swizzled by row bits 1-2 ((l>>3)&3) so stored slot = c ^ ((r>>1)&3)
    const int srow  = l >> 2;
    const int selem = (((l & 3) ^ ((l >> 3) & 3))) << 3;

    // fragment-read: chunk hi4 of row r at slot hi4 ^ ((r>>1)&3); r ≡ lo16 (16)
    const int lo16 = l & 15, hi4 = l >> 4;
    const int fco = ((hi4 ^ ((lo16 >> 1) & 3))) << 3;

    // segment tables packed as nibbles: A {0,1,2,0,1,0}, B {0,0,0,1,1,2}
#define STAGE(tt, mat, kk) do {                                               \
    const int seg_ = (tt) >> 2;                                               \
    const unsigned short* S_ = (mat)                                          \
        ? cp + (size_t)((0x211000 >> (seg_ << 2)) & 3) * 262144u              \
        : zp + (size_t)((0x010210 >> (seg_ << 2)) & 3) * 8388608u;            \
    const int R_  = (mat) ? brow : arow;                                      \
    const int KO_ = (((tt) & 3) << 6) + ((kk) << 5) + selem;                  \
    GL2LDS(S_ + (size_t)(R_ + (w * 2 + 0) * 16 + srow) * 256 + KO_,           \
           &Ld[(tt) & 1][mat][kk][(w * 2 + 0) * 512]);                        \
    GL2LDS(S_ + (size_t)(R_ + (w * 2 + 1) * 16 + srow) * 256 + KO_,           \
           &Ld[(tt) & 1][mat][kk][(w * 2 + 1) * 512]);                        \
} while (0)

#define VM4  asm volatile("s_waitcnt vmcnt(4)"  ::: "memory")
#define VM0  asm volatile("s_waitcnt vmcnt(0)"  ::: "memory")
#define NOPS ((void)0)
#define FNCE do { asm volatile("" ::: "memory");                              \
                  __builtin_amdgcn_sched_barrier(0); } while (0)
#define SBAR do { asm volatile("" ::: "memory");                              \
                  __builtin_amdgcn_s_barrier();                               \
                  __builtin_amdgcn_sched_barrier(0); } while (0)

#define PH(t, mh, kk, STAGESTMT, VMSTMT, BARSTMT) do {                        \
    const unsigned short* Ap_ = &Ld[(t) & 1][0][kk][0];                       \
    const unsigned short* Bp_ = &Ld[(t) & 1][1][kk][0];                       \
    bf16x8 a0, a1, a2, a3, b0, b1, b2, b3;                                    \
    a0 = *(const bf16x8*)&Ap_[(wr*128 + ((mh)*4+0)*16 + lo16)*32 + fco];      \
    a1 = *(const bf16x8*)&Ap_[(wr*128 + ((mh)*4+1)*16 + lo16)*32 + fco];      \
    a2 = *(const bf16x8*)&Ap_[(wr*128 + ((mh)*4+2)*16 + lo16)*32 + fco];      \
    a3 = *(const bf16x8*)&Ap_[(wr*128 + ((mh)*4+3)*16 + lo16)*32 + fco];      \
    b0 = *(const bf16x8*)&Bp_[(wc*64 + 0*16 + lo16)*32 + fco];                \
    b1 = *(const bf16x8*)&Bp_[(wc*64 + 1*16 + lo16)*32 + fco];                \
    b2 = *(const bf16x8*)&Bp_[(wc*64 + 2*16 + lo16)*32 + fco];                \
    b3 = *(const bf16x8*)&Bp_[(wc*64 + 3*16 + lo16)*32 + fco];                \
    STAGESTMT;                                                                \
    FNCE;                                                                     \
    __builtin_amdgcn_s_setprio(1);                                            \
    acc[(mh)*4+0][0] = __builtin_amdgcn_mfma_f32_16x16x32_bf16(a0, b0, acc[(mh)*4+0][0], 0,0,0); \
    acc[(mh)*4+0][1] = __builtin_amdgcn_mfma_f32_16x16x32_bf16(a0, b1, acc[(mh)*4+0][1], 0,0,0); \
    acc[(mh)*4+0][2] = __builtin_amdgcn_mfma_f32_16x16x32_bf16(a0, b2, acc[(mh)*4+0][2], 0,0,0); \
    acc[(mh)*4+0][3] = __builtin_amdgcn_mfma_f32_16x16x32_bf16(a0, b3, acc[(mh)*4+0][3], 0,0,0); \
    acc[(mh)*4+1][0] = __builtin_amdgcn_mfma_f32_16x16x32_bf16(a1, b0, acc[(mh)*4+1][0], 0,0,0); \
    acc[(mh)*4+1][1] = __builtin_amdgcn_mfma_f32_16x16x32_bf16(a1, b1, acc[(mh)*4+1][1], 0,0,0); \
    acc[(mh)*4+1][2] = __builtin_amdgcn_mfma_f32_16x16x32_bf16(a1, b2, acc[(mh)*4+1][2], 0,0,0); \
    acc[(mh)*4+1][3] = __builtin_amdgcn_mfma_f32_16x16x32_bf16(a1, b3, acc[(mh)*4+1][3], 0,0,0); \
    acc[(mh)*4+2][0] = __builtin_amdgcn_mfma_f32_16x16x32_bf16(a2, b0, acc[(mh)*4+2][0], 0,0,0); \
    acc[(mh)*4+2][1] = __builtin_amdgcn_mfma_f32_16x16x32_bf16(a2, b1, acc[(mh)*4+2][1], 0,0,0); \
    acc[(mh)*4+2][2] = __builtin_amdgcn_mfma_f32_16x16x32_bf16(a2, b2, acc[(mh)*4+2][2], 0,0,0); \
    acc[(mh)*4+2][3] = __builtin_amdgcn_mfma_f32_16x16x32_bf16(a2, b3, acc[(mh)*4+2][3], 0,0,0); \
    acc[(mh)*4+3][0] = __builtin_amdgcn_mfma_f32_16x16x32_bf16(a3, b0, acc[(mh)*4+3][0], 0,0,0); \
    acc[(mh)*4+3][1] = __builtin_amdgcn_mfma_f32_16x16x32_bf16(a3, b1, acc[(mh)*4+3][1], 0,0,0); \
    acc[(mh)*4+3][2] = __builtin_amdgcn_mfma_f32_16x16x32_bf16(a3, b2, acc[(mh)*4+3][2], 0,0,0); \
    acc[(mh)*4+3][3] = __builtin_amdgcn_mfma_f32_16x16x32_bf16(a3, b3, acc[(mh)*4+3][3], 0,0,0); \
    __builtin_amdgcn_s_setprio(0);                                            \
    VMSTMT;                                                                   \
    BARSTMT;                                                                  \
} while (0)

    // barriers ONLY after the two vmcnt points (cross-wave staging sync)
#define TILE(t, SA0, SB0, SA1, SB1, V2, V4)                                   \
    PH(t, 0, 0, SA0, NOPS, FNCE);                                             \
    PH(t, 1, 0, SB0, V2,   SBAR);                                             \
    PH(t, 0, 1, SA1, NOPS, FNCE);                                             \
    PH(t, 1, 1, SB1, V4,   SBAR)

    // prologue: stage tile 0 fully; wait its kk0 (leave kk1's 4); barrier
    STAGE(0, 0, 0); STAGE(0, 1, 0); STAGE(0, 0, 1); STAGE(0, 1, 1);
    VM4;
    SBAR;

#pragma unroll 2
    for (int t = 0; t <= 22; ++t) {
        TILE(t, STAGE(t + 1, 0, 0), STAGE(t + 1, 1, 0),
                STAGE(t + 1, 0, 1), STAGE(t + 1, 1, 1), VM4, VM4);
    }
    TILE(23, NOPS, NOPS, NOPS, NOPS, VM0, NOPS);

#undef TILE
#undef PH
#undef STAGE

    // epilogue: fused argmin. col = brow + wc*64 + n*16 + lo16
    int coln[4]; float cnv[4];
#pragma unroll
    for (int n = 0; n < 4; ++n) {
        coln[n] = brow + wc * 64 + n * 16 + lo16;
        cnv[n] = cnorm[coln[n]];
    }
#pragma unroll
    for (int m = 0; m < 8; ++m) {
#pragma unroll
        for (int j = 0; j < 4; ++j) {
            unsigned long long best = 0xFFFFFFFFFFFFFFFFull;
#pragma unroll
            for (int n = 0; n < 4; ++n) {
                float d = fmaf(-2.0f, acc[m][n][j], cnv[n]);
                unsigned u = __float_as_uint(d);
                u = (u & 0x80000000u) ? ~u : (u | 0x80000000u);   // order-preserving map
                unsigned long long pk = ((unsigned long long)u << 32) | (unsigned)coln[n];
                best = pk < best ? pk : best;
            }
#pragma unroll
            for (int mask = 1; mask <= 8; mask <<= 1) {
                unsigned long long o = __shfl_xor(best, mask, 64);
                best = o < best ? o : best;
            }
            if (lo16 == 0) {
                const int row = arow + wr * 128 + m * 16 + hi4 * 4 + j;
                atomicMin(&packed[row], best);
            }
        }
    }
}

// ---------------------------------------------------------------------------
// gather (packed): z_q write, out_idx write, vq_loss accumulate
// ---------------------------------------------------------------------------
__global__ __launch_bounds__(256, 2)
void vq_gather_packed_kernel(const float* __restrict__ cb, const float* __restrict__ z,
                             const unsigned long long* __restrict__ packed,
                             float* __restrict__ out_zq, float* __restrict__ out_idx,
                             float* __restrict__ loss)
{
    __shared__ float rows[64 * 257];
    __shared__ int   ks[64];
    __shared__ float wsum[4];

    const int t   = threadIdx.x;
    const int blk = blockIdx.x;            // 512 blocks
    const int b   = blk >> 4;
    const int hw0 = (blk & 15) << 6;
    const int n0  = blk << 6;

    if (t < 64) {
        const int k = (int)(packed[n0 + t] & 0xFFFFFFFFull);
        ks[t] = k;
        out_idx[n0 + t] = (float)k;
    }
    __syncthreads();

#pragma unroll 4
    for (int i = 0; i < 64; ++i) {
        rows[i * 257 + t] = cb[(size_t)ks[i] * 256 + t];
    }
    __syncthreads();

    const int dq = t >> 6;
    const int hw = t & 63;
    const size_t obase = ((size_t)b << 18) + hw0 + hw;
    float sum = 0.f;
#pragma unroll 4
    for (int dd = 0; dd < 64; ++dd) {
        const int d = (dq << 6) + dd;
        const float  q  = rows[hw * 257 + d];
        const size_t a  = obase + (size_t)d * 1024;
        const float  zv = z[a];
        out_zq[a] = q;
        const float diff = q - zv;
        sum = fmaf(diff, diff, sum);
    }
#pragma unroll
    for (int m = 1; m <= 32; m <<= 1) sum += __shfl_xor(sum, m, 64);
    if ((t & 63) == 0) wsum[t >> 6] = sum;
    __syncthreads();
    if (t == 0) {
        const float s = (wsum[0] + wsum[1]) + (wsum[2] + wsum[3]);
        atomicAdd(loss, s * (1.25f / 8388608.0f));   // (1+0.25)*SSE/(B*D*H*W)
    }
}

// ===========================================================================
// FALLBACK PATH (ws too small): round-3 fp32 VALU kernels, known-passing.
// ===========================================================================
__global__ __launch_bounds__(256)
void vq_transpose_kernel(const float* __restrict__ cb, float* __restrict__ ctT)
{
    __shared__ float tile[64 * 65];
    const int t  = threadIdx.x;
    const int kb = blockIdx.x >> 2, db = blockIdx.x & 3;
    const int k0 = kb << 6, d0 = db << 6;
#pragma unroll
    for (int i = 0; i < 16; ++i) {
        int idx = i * 256 + t;
        int r = idx >> 6, c = idx & 63;
        tile[r * 65 + c] = cb[(size_t)(k0 + r) * 256 + d0 + c];
    }
    __syncthreads();
#pragma unroll
    for (int i = 0; i < 16; ++i) {
        int idx = i * 256 + t;
        int r = idx >> 6, c = idx & 63;
        ctT[(size_t)(d0 + r) * 1024 + k0 + c] = tile[c * 65 + r];
    }
}

__global__ __launch_bounds__(256)
void vq_cnorm_fb_kernel(const float* __restrict__ cb, float* __restrict__ cnorm)
{
    const int k = blockIdx.x * 256 + threadIdx.x;  // grid=4
    const float4* row = reinterpret_cast<const float4*>(cb + (size_t)k * 256);
    float s0 = 0.f, s1 = 0.f, s2 = 0.f, s3 = 0.f;
#pragma unroll 8
    for (int i = 0; i < 64; ++i) {
        float4 v = row[i];
        s0 = fmaf(v.x, v.x, s0);
        s1 = fmaf(v.y, v.y, s1);
        s2 = fmaf(v.z, v.z, s2);
        s3 = fmaf(v.w, v.w, s3);
    }
    cnorm[k] = (s0 + s1) + (s2 + s3);
}

__global__ __launch_bounds__(512, 2)
void vq_argmin_kernel(const float* __restrict__ z, const float* __restrict__ ctT,
                      const float* __restrict__ cnorm, int* __restrict__ codes,
                      float* __restrict__ out_idx)
{
    __shared__ float zt[256 * 64];
    __shared__ float ct[16 * 256];
    const int t = threadIdx.x, tx = t & 63, ty = t >> 6, p0 = ty << 3;
    const int blk = blockIdx.x, b = blk >> 4, hw0 = (blk & 15) << 6;
    const float* zbase = z + ((size_t)b << 18) + hw0;
#pragma unroll
    for (int i = 0; i < 8; ++i) {
        int idx = i * 512 + t;
        int d = idx >> 4, c4 = (idx & 15) << 2;
        float4 v = *reinterpret_cast<const float4*>(zbase + (size_t)d * 1024 + c4);
        *reinterpret_cast<float4*>(&zt[d * 64 + c4]) = v;
    }
    float minv[8]; int mini[8];
#pragma unroll
    for (int i = 0; i < 8; ++i) { minv[i] = 3.0e38f; mini[i] = 0; }
    const float* zrd = &zt[p0];
    const float* crd = &ct[tx << 2];
    for (int kt = 0; kt < 4; ++kt) {
        const int k0 = kt << 8;
        float acc[8][4];
#pragma unroll
        for (int i = 0; i < 8; ++i)
#pragma unroll
            for (int j = 0; j < 4; ++j) acc[i][j] = 0.f;
        for (int dc = 0; dc < 16; ++dc) {
            const int d0 = dc << 4;
            __syncthreads();
#pragma unroll
            for (int i = 0; i < 2; ++i) {
                int idx = i * 512 + t;
                int r = idx >> 6, c4 = (idx & 63) << 2;
                float4 v = *reinterpret_cast<const float4*>(ctT + (size_t)(d0 + r) * 1024 + k0 + c4);
                *reinterpret_cast<float4*>(&ct[r * 256 + c4]) = v;
            }
            __syncthreads();
            const float* zp = zrd + d0 * 64;
#pragma unroll
            for (int d = 0; d < 16; ++d) {
                float4 za = *reinterpret_cast<const float4*>(zp + d * 64);
                float4 zb = *reinterpret_cast<const float4*>(zp + d * 64 + 4);
                float4 cc = *reinterpret_cast<const float4*>(crd + d * 256);
#define VQ_FMA_ROW(ii, zv)                          \
                acc[ii][0] = fmaf(zv, cc.x, acc[ii][0]); \
                acc[ii][1] = fmaf(zv, cc.y, acc[ii][1]); \
                acc[ii][2] = fmaf(zv, cc.z, acc[ii][2]); \
                acc[ii][3] = fmaf(zv, cc.w, acc[ii][3]);
                VQ_FMA_ROW(0, za.x) VQ_FMA_ROW(1, za.y) VQ_FMA_ROW(2, za.z) VQ_FMA_ROW(3, za.w)
                VQ_FMA_ROW(4, zb.x) VQ_FMA_ROW(5, zb.y) VQ_FMA_ROW(6, zb.z) VQ_FMA_ROW(7, zb.w)
#undef VQ_FMA_ROW
            }
        }
#pragma unroll
        for (int j = 0; j < 4; ++j) {
            const int k = k0 + (tx << 2) + j;
            const float cn = cnorm[k];
#pragma unroll
            for (int i = 0; i < 8; ++i) {
                float dist = fmaf(-2.0f, acc[i][j], cn);
                if (dist < minv[i]) { minv[i] = dist; mini[i] = k; }
            }
        }
    }
#pragma unroll
    for (int m = 1; m <= 32; m <<= 1) {
#pragma unroll
        for (int i = 0; i < 8; ++i) {
            float ov = __shfl_xor(minv[i], m, 64);
            int   oi = __shfl_xor(mini[i], m, 64);
            if (ov < minv[i] || (ov == minv[i] && oi < mini[i])) { minv[i] = ov; mini[i] = oi; }
        }
    }
    if (tx == 0) {
        const int n0 = (blk << 6) + p0;
#pragma unroll
        for (int i = 0; i < 8; ++i) {
            codes[n0 + i]   = mini[i];
            out_idx[n0 + i] = (float)mini[i];
        }
    }
}

__global__ __launch_bounds__(256, 2)
void vq_gather_kernel(const float* __restrict__ cb, const float* __restrict__ z,
                      const int* __restrict__ codes, float* __restrict__ out_zq,
                      float* __restrict__ loss)
{
    __shared__ float rows[64 * 257];
    __shared__ int   ks[64];
    __shared__ float wsum[4];
    const int t = threadIdx.x, blk = blockIdx.x;
    const int b = blk >> 4, hw0 = (blk & 15) << 6, n0 = blk << 6;
    if (t < 64) ks[t] = codes[n0 + t];
    __syncthreads();
#pragma unroll 4
    for (int i = 0; i < 64; ++i) rows[i * 257 + t] = cb[(size_t)ks[i] * 256 + t];
    __syncthreads();
    const int dq = t >> 6, hw = t & 63;
    const size_t obase = ((size_t)b << 18) + hw0 + hw;
    float sum = 0.f;
#pragma unroll 4
    for (int dd = 0; dd < 64; ++dd) {
        const int d = (dq << 6) + dd;
        const float  q  = rows[hw * 257 + d];
        const size_t a  = obase + (size_t)d * 1024;
        const float  zv = z[a];
        out_zq[a] = q;
        const float diff = q - zv;
        sum = fmaf(diff, diff, sum);
    }
#pragma unroll
    for (int m = 1; m <= 32; m <<= 1) sum += __shfl_xor(sum, m, 64);
    if ((t & 63) == 0) wsum[t >> 6] = sum;
    __syncthreads();
    if (t == 0) {
        const float s = (wsum[0] + wsum[1]) + (wsum[2] + wsum[3]);
        atomicAdd(loss, s * (1.25f / 8388608.0f));
    }
}

// ---------------------------------------------------------------------------
extern "C" void kernel_launch(void* const* d_in, const int* in_sizes, int n_in,
                              void* d_out, int out_size, void* d_ws, size_t ws_size,
                              hipStream_t stream)
{
    (void)in_sizes; (void)n_in; (void)out_size;

    const float* z  = (const float*)d_in[0];   // 32*256*32*32 fp32
    const float* cb = (const float*)d_in[1];   // 1024*256 fp32

    float* out      = (float*)d_out;
    float* out_zq   = out;                     // 8388608
    float* out_idx  = out + 8388608;           // 32768 (indices as float values)
    float* out_loss = out + 8421376;           // 1

    // MFMA-path workspace: packed(256KB) | z0|z1|z2 (16MB each) | c0|c1|c2 | cnorm
    const size_t NEED = 262144ull + 3ull * 16777216ull + 3ull * 524288ull + 4096ull;

    if (ws_size >= NEED) {
        unsigned long long* packed = (unsigned long long*)d_ws;
        unsigned short* z0 = (unsigned short*)((char*)d_ws + 262144);
        unsigned short* z1 = z0 + 8388608u;
        unsigned short* z2 = z1 + 8388608u;
        unsigned short* c0 = z2 + 8388608u;
        unsigned short* c1 = c0 + 262144u;
        unsigned short* c2 = c1 + 262144u;
        float* cnorm = (float*)(c2 + 262144u);

        vq_csplit_kernel<<<256, 256, 0, stream>>>(cb, c0, c1, c2, packed, out_loss);
        vq_cnorm_kernel<<<4, 256, 0, stream>>>(cb, cnorm);
        vq_zsplit_kernel<<<512, 256, 0, stream>>>(z, z0, z1, z2);
        vq_mfma_argmin_kernel<<<512, 512, 0, stream>>>(z0, c0, cnorm, packed);
        vq_gather_packed_kernel<<<512, 256, 0, stream>>>(cb, z, packed, out_zq, out_idx, out_loss);
    } else {
        // fallback: round-3 fp32 path (ws >= 1.38MB known OK)
        float* ctT   = (float*)d_ws;
        float* cnorm = ctT + 256 * 1024;
        int*   codes = (int*)(cnorm + 1024);

        hipMemsetAsync(out_loss, 0, sizeof(float), stream);
        vq_transpose_kernel<<<64, 256, 0, stream>>>(cb, ctT);
        vq_cnorm_fb_kernel<<<4, 256, 0, stream>>>(cb, cnorm);
        vq_argmin_kernel<<<512, 512, 0, stream>>>(z, ctT, cnorm, codes, out_idx);
        vq_gather_kernel<<<512, 256, 0, stream>>>(cb, z, codes, out_zq, out_loss);
    }
}